// Round 5
// baseline (732.082 us; speedup 1.0000x reference)
//
#include <hip/hip_runtime.h>

// Regrid, fully fused: y[n, b] = sum_{k: rows[k]==b} w[k] * x[n, flip(cols[k])]
// x: (140, 721*1440) f32, rows/cols: (260640,) i32, w: f32, out: (140, 181*360) f32.
//
// Preproc per call: row-histogram -> 1-block scan (roff) -> permute (cf,w,row)
// into row-sorted order. Hot phase: ONE kernel, block = 64 aligned output rows
// x 16-field chunk; gathers x directly (per-chunk working set 66MB is
// LLC-resident, so random 4B re-reads of a 64B line hit cache; each line comes
// from HBM once), accumulates into a 4KB LDS tile, flushes with plain
// coalesced stores. No g intermediate, no global atomics in the hot path,
// d_out fully overwritten so no zeroing needed.

#define NXS 1440
#define NYS 721
#define N_A_CONST (721 * 1440)
#define N_B_CONST (181 * 360)
#define CHUNK 16
#define RPB 64          // output rows per block

__device__ __forceinline__ int flip_col(int c) {
    int iy = c / NXS;
    int ix = c - iy * NXS;
    return (NYS - 1 - iy) * NXS + ix;
}

// ---------- preprocessing ----------

__global__ void zero_ws_kernel(int* __restrict__ p, int n) {
    int i = blockIdx.x * blockDim.x + threadIdx.x;
    int stride = gridDim.x * blockDim.x;
    for (; i < n; i += stride) p[i] = 0;
}

__global__ void hist_rows_kernel(const int* __restrict__ rows, int* __restrict__ rcount,
                                 int nnz) {
    int k = blockIdx.x * blockDim.x + threadIdx.x;
    if (k >= nnz) return;
    atomicAdd(&rcount[rows[k]], 1);
}

// 1 block, 1024 threads x 64 serial elems (covers 65536 >= N_B+1).
// Exclusive scan rcount -> roff; roff[N_B] = total.
__global__ void scan_roff_kernel(const int* __restrict__ rcount, int* __restrict__ roff) {
    const int n = N_B_CONST;
    int t = threadIdx.x;
    int base = t * 64;
    int s = 0;
    for (int i = 0; i < 64; ++i) {
        int idx = base + i;
        s += (idx < n) ? rcount[idx] : 0;
    }
    int lane = t & 63;
    int wv = t >> 6;
    int incl = s;
    #pragma unroll
    for (int off = 1; off < 64; off <<= 1) {
        int u = __shfl_up(incl, off, 64);
        if (lane >= off) incl += u;
    }
    __shared__ int wsum[16];
    if (lane == 63) wsum[wv] = incl;
    __syncthreads();
    if (t < 16) {
        int v = wsum[t];
        #pragma unroll
        for (int off = 1; off < 16; off <<= 1) {
            int u = __shfl_up(v, off, 16);
            if (t >= off) v += u;
        }
        wsum[t] = v;
    }
    __syncthreads();
    int waveoff = (wv == 0) ? 0 : wsum[wv - 1];
    int run = waveoff + incl - s;
    for (int i = 0; i < 64; ++i) {
        int idx = base + i;
        if (idx < n) { roff[idx] = run; run += rcount[idx]; }
    }
    if (t == 1023) roff[n] = run;
}

// Permute (cf, w, row) into row-sorted order (order within a row irrelevant).
__global__ void perm_kernel(const int* __restrict__ rows, const int* __restrict__ cols,
                            const float* __restrict__ w,
                            const int* __restrict__ roff, int* __restrict__ rcur,
                            int4* __restrict__ perm, int nnz) {
    int k = blockIdx.x * blockDim.x + threadIdx.x;
    if (k >= nnz) return;
    int b = rows[k];
    int j = roff[b] + atomicAdd(&rcur[b], 1);
    perm[j] = make_int4(flip_col(cols[k]), __float_as_int(w[k]), b, 0);
}

// ---------- hot phase: one dispatch ----------

__global__ void fused_kernel(const float* __restrict__ x, const int4* __restrict__ perm,
                             const int* __restrict__ roff, float* __restrict__ out,
                             int nfield) {
    __shared__ float acc[CHUNK * RPB];          // field-major: acc[c*64 + rr], 4KB
    int r0 = blockIdx.x * RPB;
    int chunk = blockIdx.y;
    int n0 = chunk * CHUNK;
    int C = nfield - n0; if (C > CHUNK) C = CHUNK;

    #pragma unroll
    for (int i = threadIdx.x; i < CHUNK * RPB; i += 256) acc[i] = 0.0f;

    int rend = r0 + RPB; if (rend > N_B_CONST) rend = N_B_CONST;
    int j0 = roff[r0], j1 = roff[rend];
    __syncthreads();

    const float* xc = x + (size_t)n0 * N_A_CONST;
    for (int j = j0 + (int)threadIdx.x; j < j1; j += 256) {
        int4 p = perm[j];
        int cf = p.x;
        float wj = __int_as_float(p.y);
        int rr = p.z - r0;
        #pragma unroll
        for (int c = 0; c < CHUNK; ++c) {
            if (c < C) {
                float v = wj * xc[(size_t)c * N_A_CONST + cf];
                atomicAdd(&acc[c * RPB + rr], v);
            }
        }
    }
    __syncthreads();

    // flush: idx -> (c = idx/64, rr = idx%64); consecutive lanes ->
    // consecutive LDS banks and consecutive global addresses.
    for (int idx = threadIdx.x; idx < CHUNK * RPB; idx += 256) {
        int c = idx >> 6;
        int rr = idx & 63;
        int b = r0 + rr;
        if (c < C && b < N_B_CONST)
            out[(size_t)(n0 + c) * N_B_CONST + b] = acc[idx];
    }
}

// ---------- fallback (only if ws is absurdly small) ----------

__global__ void scatter_fallback_kernel(const float* __restrict__ x, const int* __restrict__ rows,
                                        const int* __restrict__ cols, const float* __restrict__ w,
                                        float* __restrict__ out, int nnz) {
    int k = blockIdx.x * blockDim.x + threadIdx.x;
    if (k >= nnz) return;
    int n = blockIdx.y;
    int cf = flip_col(cols[k]);
    float v = w[k] * x[(size_t)n * N_A_CONST + cf];
    atomicAdd(out + (size_t)n * N_B_CONST + rows[k], v);
}

__global__ void zero_out_kernel(float* __restrict__ out, int n) {
    int i = blockIdx.x * blockDim.x + threadIdx.x;
    int stride = gridDim.x * blockDim.x;
    for (; i < n; i += stride) out[i] = 0.0f;
}

extern "C" void kernel_launch(void* const* d_in, const int* in_sizes, int n_in,
                              void* d_out, int out_size, void* d_ws, size_t ws_size,
                              hipStream_t stream) {
    const float* x    = (const float*)d_in[0];
    const int*   rows = (const int*)d_in[1];
    const int*   cols = (const int*)d_in[2];
    const float* w    = (const float*)d_in[3];
    float* out = (float*)d_out;

    int nnz    = in_sizes[1];
    int nfield = in_sizes[0] / N_A_CONST;   // 140
    int nchunk = (nfield + CHUNK - 1) / CHUNK;

    // ws layout (int units). rcount/rcur first: zeroed by one kernel.
    size_t o = 0;
    size_t rcount_o = o; o += N_B_CONST;
    size_t rcur_o   = o; o += N_B_CONST;
    size_t zero_span = o;
    size_t roff_o   = o; o += N_B_CONST + 1;
    o = (o + 3) & ~(size_t)3;                  // 16B-align perm
    size_t perm_o   = o; o += 4 * (size_t)nnz; // int4
    size_t need_bytes = o * sizeof(int);

    if (ws_size < need_bytes) {
        zero_out_kernel<<<2048, 256, 0, stream>>>(out, out_size);
        dim3 grid((nnz + 255) / 256, nfield);
        scatter_fallback_kernel<<<grid, 256, 0, stream>>>(x, rows, cols, w, out, nnz);
        return;
    }

    int*  wsI    = (int*)d_ws;
    int*  rcount = wsI + rcount_o;
    int*  rcur   = wsI + rcur_o;
    int*  roff   = wsI + roff_o;
    int4* perm   = (int4*)(wsI + perm_o);

    zero_ws_kernel<<<512, 256, 0, stream>>>(wsI, (int)zero_span);

    int nblk = (nnz + 255) / 256;
    hist_rows_kernel<<<nblk, 256, 0, stream>>>(rows, rcount, nnz);
    scan_roff_kernel<<<1, 1024, 0, stream>>>(rcount, roff);
    perm_kernel<<<nblk, 256, 0, stream>>>(rows, cols, w, roff, rcur, perm, nnz);

    dim3 fgrid((N_B_CONST + RPB - 1) / RPB, nchunk);   // (1019, 9)
    fused_kernel<<<fgrid, 256, 0, stream>>>(x, perm, roff, out, nfield);
}

// Round 6
// 409.838 us; speedup vs baseline: 1.7863x; 1.7863x over previous
//
#include <hip/hip_runtime.h>

// Regrid as two-phase streaming SpMM with wave-cooperative gather.
// y[n, b] = sum_{k: rows[k]==b} w[k] * x[n, flip(cols[k])]
// x: (140, 721*1440) f32, rows/cols: (260640,) i32, w: f32, out: (140, 181*360) f32.
//
// Preproc: bucket(=64B x line) histogram + row histogram -> 2-block scan ->
// one permute pass producing perm[j_cf] = (cf, w, j_row) where j_cf is
// cf-line-sorted (gather order) and j_row is row-sorted (reduce order).
// Gather: wave owns 4 aligned x lines (64 floats); loads them 256B-coalesced
// for 16 fields, redistributes to nnz lanes via __shfl, stores each nnz's
// 16-field product line to g[j_row] (store-side permute). Reduce: thread
// (b, quad) reads g rows SEQUENTIALLY (no jlist) and writes out.
// No global atomics in hot phases; d_out fully overwritten -> no zeroing.

#define NXS 1440
#define NYS 721
#define N_A_CONST (721 * 1440)
#define N_B_CONST (181 * 360)
#define NBUCK (N_A_CONST / 16)   // 64,890 64B-line buckets (divides exactly)
#define CHUNK 16

__device__ __forceinline__ int flip_col(int c) {
    int iy = c / NXS;
    int ix = c - iy * NXS;
    return (NYS - 1 - iy) * NXS + ix;
}

// ---------- preprocessing ----------

__global__ void zero_ws_kernel(int* __restrict__ p, int n) {
    int i = blockIdx.x * blockDim.x + threadIdx.x;
    int stride = gridDim.x * blockDim.x;
    for (; i < n; i += stride) p[i] = 0;
}

__global__ void hist2_kernel(const int* __restrict__ rows, const int* __restrict__ cols,
                             int* __restrict__ bcount, int* __restrict__ rcount, int nnz) {
    int k = blockIdx.x * blockDim.x + threadIdx.x;
    if (k >= nnz) return;
    int cf = flip_col(cols[k]);
    atomicAdd(&bcount[cf >> 4], 1);
    atomicAdd(&rcount[rows[k]], 1);
}

// block 0: bcount->boff (NBUCK); block 1: rcount->roff (N_B). 1024 thr x 64 elems.
__global__ void scan2_kernel(const int* __restrict__ bcount, int* __restrict__ boff,
                             const int* __restrict__ rcount, int* __restrict__ roff) {
    const int* in; int* out; int n;
    if (blockIdx.x == 0) { in = bcount; out = boff; n = NBUCK; }
    else                 { in = rcount; out = roff; n = N_B_CONST; }

    int t = threadIdx.x;
    int base = t * 64;
    int s = 0;
    for (int i = 0; i < 64; ++i) {
        int idx = base + i;
        s += (idx < n) ? in[idx] : 0;
    }
    int lane = t & 63;
    int wv = t >> 6;
    int incl = s;
    #pragma unroll
    for (int off = 1; off < 64; off <<= 1) {
        int u = __shfl_up(incl, off, 64);
        if (lane >= off) incl += u;
    }
    __shared__ int wsum[16];
    if (lane == 63) wsum[wv] = incl;
    __syncthreads();
    if (t < 16) {
        int v = wsum[t];
        #pragma unroll
        for (int off = 1; off < 16; off <<= 1) {
            int u = __shfl_up(v, off, 16);
            if (t >= off) v += u;
        }
        wsum[t] = v;
    }
    __syncthreads();
    int waveoff = (wv == 0) ? 0 : wsum[wv - 1];
    int run = waveoff + incl - s;
    for (int i = 0; i < 64; ++i) {
        int idx = base + i;
        if (idx < n) { out[idx] = run; run += in[idx]; }
    }
    if (t == 1023) out[n] = run;   // base 65472 >= n for both arrays -> total
}

// One pass: perm[j_cf] = (cf, w_bits, j_row). j_cf bucket-sorted, j_row row-sorted.
__global__ void perm2_kernel(const int* __restrict__ rows, const int* __restrict__ cols,
                             const float* __restrict__ w,
                             const int* __restrict__ boff, int* __restrict__ bcur,
                             const int* __restrict__ roff, int* __restrict__ rcur,
                             int4* __restrict__ perm, int nnz) {
    int k = blockIdx.x * blockDim.x + threadIdx.x;
    if (k >= nnz) return;
    int cf = flip_col(cols[k]);
    int bu = cf >> 4;
    int j_cf = boff[bu] + atomicAdd(&bcur[bu], 1);
    int b = rows[k];
    int j_row = roff[b] + atomicAdd(&rcur[b], 1);
    perm[j_cf] = make_int4(cf, __float_as_int(w[k]), j_row, 0);
}

// ---------- hot phases ----------

// Wave owns buckets bu0..bu0+3 (64 consecutive floats per field). Loads are
// 256B-coalesced per field; nnz served via __shfl from the holding lane;
// each nnz's 16-field product line stored to g[j_row] (64B, one lane).
__global__ void gatherw_kernel(const float* __restrict__ x, const int4* __restrict__ perm,
                               const int* __restrict__ boff, float* __restrict__ g,
                               int nnz, int nfield) {
    int chunk = blockIdx.y;
    int n0 = chunk * CHUNK;
    int C = nfield - n0; if (C > CHUNK) C = CHUNK;

    int wid = (blockIdx.x * 256 + (int)threadIdx.x) >> 6;
    int lane = threadIdx.x & 63;
    int bu0 = wid * 4;
    if (bu0 >= NBUCK) return;

    int i = (bu0 << 4) + lane;                 // elem index within a field plane
    bool iok = i < N_A_CONST;
    float xv[CHUNK];
    #pragma unroll
    for (int f = 0; f < CHUNK; ++f) {
        bool ld = (f < C) && iok;
        xv[f] = ld ? x[(size_t)(n0 + f) * N_A_CONST + i] : 0.0f;
    }

    int bend = bu0 + 4; if (bend > NBUCK) bend = NBUCK;
    int s = boff[bu0], e = boff[bend];
    float* gc = g + (size_t)chunk * nnz * CHUNK;

    for (int base = s; base < e; base += 64) {
        int j = base + lane;
        bool act = j < e;
        int4 p = perm[act ? j : s];
        int src = (p.x - (bu0 << 4)) & 63;     // holding lane of this cf
        float wj = __int_as_float(p.y);
        float pv[CHUNK];
        #pragma unroll
        for (int f = 0; f < CHUNK; ++f)
            pv[f] = wj * __shfl(xv[f], src, 64);
        if (act) {
            float4* gp = (float4*)(gc + (size_t)p.z * CHUNK);
            gp[0] = make_float4(pv[0],  pv[1],  pv[2],  pv[3]);
            gp[1] = make_float4(pv[4],  pv[5],  pv[6],  pv[7]);
            gp[2] = make_float4(pv[8],  pv[9],  pv[10], pv[11]);
            gp[3] = make_float4(pv[12], pv[13], pv[14], pv[15]);
        }
    }
}

// Thread (b, q): g rows for b are contiguous [roff[b], roff[b+1]) -> fully
// sequential reads; 4 lanes per 64B g line; coalesced out stores per quad.
__global__ void reduceseq_kernel(const float* __restrict__ g, const int* __restrict__ roff,
                                 float* __restrict__ out, int nnz, int nfield) {
    int tid = blockIdx.x * blockDim.x + threadIdx.x;
    int b = tid >> 2;
    int q = tid & 3;
    if (b >= N_B_CONST) return;
    int chunk = blockIdx.y;
    int n0 = chunk * CHUNK;
    int C = nfield - n0; if (C > CHUNK) C = CHUNK;

    const float* gc = g + (size_t)chunk * nnz * CHUNK;
    int p0 = roff[b], p1 = roff[b + 1];
    float4 acc = make_float4(0.f, 0.f, 0.f, 0.f);
    for (int pos = p0; pos < p1; ++pos) {
        float4 a = *(const float4*)(gc + (size_t)pos * CHUNK + 4 * q);
        acc.x += a.x; acc.y += a.y; acc.z += a.z; acc.w += a.w;
    }
    int f0 = 4 * q;
    if (f0 + 0 < C) out[(size_t)(n0 + f0 + 0) * N_B_CONST + b] = acc.x;
    if (f0 + 1 < C) out[(size_t)(n0 + f0 + 1) * N_B_CONST + b] = acc.y;
    if (f0 + 2 < C) out[(size_t)(n0 + f0 + 2) * N_B_CONST + b] = acc.z;
    if (f0 + 3 < C) out[(size_t)(n0 + f0 + 3) * N_B_CONST + b] = acc.w;
}

// ---------- fallback (only if ws is absurdly small) ----------

__global__ void zero_out_kernel(float* __restrict__ out, int n) {
    int i = blockIdx.x * blockDim.x + threadIdx.x;
    int stride = gridDim.x * blockDim.x;
    for (; i < n; i += stride) out[i] = 0.0f;
}

__global__ void scatter_fallback_kernel(const float* __restrict__ x, const int* __restrict__ rows,
                                        const int* __restrict__ cols, const float* __restrict__ w,
                                        float* __restrict__ out, int nnz) {
    int k = blockIdx.x * blockDim.x + threadIdx.x;
    if (k >= nnz) return;
    int n = blockIdx.y;
    int cf = flip_col(cols[k]);
    float v = w[k] * x[(size_t)n * N_A_CONST + cf];
    atomicAdd(out + (size_t)n * N_B_CONST + rows[k], v);
}

extern "C" void kernel_launch(void* const* d_in, const int* in_sizes, int n_in,
                              void* d_out, int out_size, void* d_ws, size_t ws_size,
                              hipStream_t stream) {
    const float* x    = (const float*)d_in[0];
    const int*   rows = (const int*)d_in[1];
    const int*   cols = (const int*)d_in[2];
    const float* w    = (const float*)d_in[3];
    float* out = (float*)d_out;

    int nnz    = in_sizes[1];
    int nfield = in_sizes[0] / N_A_CONST;   // 140
    int nchunk = (nfield + CHUNK - 1) / CHUNK;

    // ws layout (int units). Count/cursor arrays first: zeroed by one kernel.
    size_t o = 0;
    size_t bcount_o = o; o += NBUCK;
    size_t bcur_o   = o; o += NBUCK;
    size_t rcount_o = o; o += N_B_CONST;
    size_t rcur_o   = o; o += N_B_CONST;
    size_t zero_span = o;
    size_t boff_o   = o; o += NBUCK + 1;
    size_t roff_o   = o; o += N_B_CONST + 1;
    o = (o + 3) & ~(size_t)3;                  // 16B-align perm
    size_t perm_o   = o; o += 4 * (size_t)nnz; // int4
    size_t g_o      = o;
    size_t need_bytes = (g_o + (size_t)nchunk * nnz * CHUNK) * sizeof(int);

    if (ws_size < need_bytes) {
        zero_out_kernel<<<2048, 256, 0, stream>>>(out, out_size);
        dim3 grid((nnz + 255) / 256, nfield);
        scatter_fallback_kernel<<<grid, 256, 0, stream>>>(x, rows, cols, w, out, nnz);
        return;
    }

    int*  wsI    = (int*)d_ws;
    int*  bcount = wsI + bcount_o;
    int*  bcur   = wsI + bcur_o;
    int*  rcount = wsI + rcount_o;
    int*  rcur   = wsI + rcur_o;
    int*  boff   = wsI + boff_o;
    int*  roff   = wsI + roff_o;
    int4* perm   = (int4*)(wsI + perm_o);
    float* g     = (float*)(wsI + g_o);

    zero_ws_kernel<<<512, 256, 0, stream>>>(wsI, (int)zero_span);

    int nblk = (nnz + 255) / 256;
    hist2_kernel<<<nblk, 256, 0, stream>>>(rows, cols, bcount, rcount, nnz);
    scan2_kernel<<<2, 1024, 0, stream>>>(bcount, boff, rcount, roff);
    perm2_kernel<<<nblk, 256, 0, stream>>>(rows, cols, w, boff, bcur, roff, rcur, perm, nnz);

    // gather: 4 buckets per wave, 4 waves per block
    int nwave = (NBUCK + 3) / 4;
    int gblk  = (nwave + 3) / 4;
    dim3 ggrid(gblk, nchunk);
    gatherw_kernel<<<ggrid, 256, 0, stream>>>(x, perm, boff, g, nnz, nfield);

    int rblk = (4 * N_B_CONST + 255) / 256;
    dim3 rgrid(rblk, nchunk);
    reduceseq_kernel<<<rgrid, 256, 0, stream>>>(g, roff, out, nnz, nfield);
}

// Round 7
// 408.280 us; speedup vs baseline: 1.7931x; 1.0038x over previous
//
#include <hip/hip_runtime.h>

// Regrid as two-phase streaming SpMM, 640B-granule permute.
// y[n, b] = sum_{k: rows[k]==b} w[k] * x[n, flip(cols[k])]
// x: (140, 721*1440) f32, rows/cols: (260640,) i32, w: f32, out: (140, 181*360) f32.
//
// Preproc: bucket(=64B x line) hist + row hist -> 2-block scan -> one permute
// pass: perm[j_cf] = (cf, w_bits, j_row); j_cf cf-line-sorted (gather order),
// j_row row-sorted (g storage order).
// Gather (1 dispatch, grid.y = 5 field-passes of 32): thread j reads perm,
// gathers 32 fields (VMEM coalescer merges the cf-sorted lanes onto ~16
// lines/instr), writes one FULL 128B line of g[j_row] per pass (row stride
// 640B = 5 lines, line-aligned). Reduce: block = 64 output rows; g is read
// FULLY SEQUENTIALLY (storage order == row order, no jlist), accumulated in
// registers, transposed through LDS, stored coalesced. No global atomics in
// hot phases; d_out fully overwritten -> no zeroing.

#define NXS 1440
#define NYS 721
#define N_A_CONST (721 * 1440)
#define N_B_CONST (181 * 360)
#define NBUCK (N_A_CONST / 16)     // 64,890 64B-line buckets (divides exactly)
#define GROW 160                   // g row stride in floats (640B = 5 x 128B lines)
#define NF_MAX 140
#define FPP 32                     // fields per gather pass

__device__ __forceinline__ int flip_col(int c) {
    int iy = c / NXS;
    int ix = c - iy * NXS;
    return (NYS - 1 - iy) * NXS + ix;
}

// ---------- preprocessing ----------

__global__ void zero_ws_kernel(int* __restrict__ p, int n) {
    int i = blockIdx.x * blockDim.x + threadIdx.x;
    int stride = gridDim.x * blockDim.x;
    for (; i < n; i += stride) p[i] = 0;
}

__global__ void hist2_kernel(const int* __restrict__ rows, const int* __restrict__ cols,
                             int* __restrict__ bcount, int* __restrict__ rcount, int nnz) {
    int k = blockIdx.x * blockDim.x + threadIdx.x;
    if (k >= nnz) return;
    int cf = flip_col(cols[k]);
    atomicAdd(&bcount[cf >> 4], 1);
    atomicAdd(&rcount[rows[k]], 1);
}

// block 0: bcount->boff (NBUCK); block 1: rcount->roff (N_B). 1024 thr x 64 elems.
__global__ void scan2_kernel(const int* __restrict__ bcount, int* __restrict__ boff,
                             const int* __restrict__ rcount, int* __restrict__ roff) {
    const int* in; int* out; int n;
    if (blockIdx.x == 0) { in = bcount; out = boff; n = NBUCK; }
    else                 { in = rcount; out = roff; n = N_B_CONST; }

    int t = threadIdx.x;
    int base = t * 64;
    int s = 0;
    for (int i = 0; i < 64; ++i) {
        int idx = base + i;
        s += (idx < n) ? in[idx] : 0;
    }
    int lane = t & 63;
    int wv = t >> 6;
    int incl = s;
    #pragma unroll
    for (int off = 1; off < 64; off <<= 1) {
        int u = __shfl_up(incl, off, 64);
        if (lane >= off) incl += u;
    }
    __shared__ int wsum[16];
    if (lane == 63) wsum[wv] = incl;
    __syncthreads();
    if (t < 16) {
        int v = wsum[t];
        #pragma unroll
        for (int off = 1; off < 16; off <<= 1) {
            int u = __shfl_up(v, off, 16);
            if (t >= off) v += u;
        }
        wsum[t] = v;
    }
    __syncthreads();
    int waveoff = (wv == 0) ? 0 : wsum[wv - 1];
    int run = waveoff + incl - s;
    for (int i = 0; i < 64; ++i) {
        int idx = base + i;
        if (idx < n) { out[idx] = run; run += in[idx]; }
    }
    if (t == 1023) out[n] = run;
}

// perm[j_cf] = (cf, w_bits, j_row, 0)
__global__ void perm2_kernel(const int* __restrict__ rows, const int* __restrict__ cols,
                             const float* __restrict__ w,
                             const int* __restrict__ boff, int* __restrict__ bcur,
                             const int* __restrict__ roff, int* __restrict__ rcur,
                             int4* __restrict__ perm, int nnz) {
    int k = blockIdx.x * blockDim.x + threadIdx.x;
    if (k >= nnz) return;
    int cf = flip_col(cols[k]);
    int bu = cf >> 4;
    int j_cf = boff[bu] + atomicAdd(&bcur[bu], 1);
    int b = rows[k];
    int j_row = roff[b] + atomicAdd(&rcur[b], 1);
    perm[j_cf] = make_int4(cf, __float_as_int(w[k]), j_row, 0);
}

// ---------- hot phases ----------

// grid = (ceil(nnz/256), 5). Pass p covers fields [32p, min(32p+32, nf)).
__global__ void gather_kernel(const float* __restrict__ x, const int4* __restrict__ perm,
                              float* __restrict__ g, int nnz, int nfield) {
    int j = blockIdx.x * blockDim.x + threadIdx.x;
    if (j >= nnz) return;
    int f0 = blockIdx.y * FPP;
    int C = nfield - f0; if (C > FPP) C = FPP;

    int4 p = perm[j];
    int cf = p.x;
    float wj = __int_as_float(p.y);
    const float* xf = x + (size_t)f0 * N_A_CONST + cf;

    float v[FPP];
    #pragma unroll
    for (int c = 0; c < FPP; ++c)
        v[c] = (c < C) ? wj * xf[(size_t)c * N_A_CONST] : 0.0f;

    float4* gp = (float4*)(g + (size_t)p.z * GROW + f0);
    #pragma unroll
    for (int i = 0; i < FPP / 4; ++i)
        if (4 * i < C)
            gp[i] = make_float4(v[4 * i], v[4 * i + 1], v[4 * i + 2], v[4 * i + 3]);
}

// Block = 64 output rows (b0..b0+63). 4 waves x 16 rows sequentially.
// g reads are fully sequential (storage order == row order). LDS transpose
// [64 rows][141] (141 coprime 32 -> conflict-free flush), coalesced out.
__global__ void reduce_kernel(const float* __restrict__ g, const int* __restrict__ roff,
                              float* __restrict__ out, int nfield) {
    __shared__ float lds[64 * 141];
    int b0 = blockIdx.x * 64;
    int lane = threadIdx.x & 63;
    int wv = threadIdx.x >> 6;

    for (int i = 0; i < 16; ++i) {
        int bl = wv * 16 + i;
        int b = b0 + bl;
        if (b >= N_B_CONST) break;
        int p0 = roff[b], p1 = roff[b + 1];
        float a0 = 0.f, a1 = 0.f, a2 = 0.f;
        for (int pos = p0; pos < p1; ++pos) {
            const float* gr = g + (size_t)pos * GROW;
            a0 += gr[lane];
            a1 += gr[64 + lane];
            if (lane < NF_MAX - 128) a2 += gr[128 + lane];
        }
        lds[bl * 141 + lane] = a0;
        lds[bl * 141 + 64 + lane] = a1;
        if (lane < NF_MAX - 128) lds[bl * 141 + 128 + lane] = a2;
    }
    __syncthreads();

    int nb = N_B_CONST - b0; if (nb > 64) nb = 64;
    for (int idx = threadIdx.x; idx < nfield * 64; idx += 256) {
        int f = idx >> 6;
        int rr = idx & 63;
        if (rr < nb)
            out[(size_t)f * N_B_CONST + b0 + rr] = lds[rr * 141 + f];
    }
}

// ---------- fallback (only if ws is absurdly small) ----------

__global__ void zero_out_kernel(float* __restrict__ out, int n) {
    int i = blockIdx.x * blockDim.x + threadIdx.x;
    int stride = gridDim.x * blockDim.x;
    for (; i < n; i += stride) out[i] = 0.0f;
}

__global__ void scatter_fallback_kernel(const float* __restrict__ x, const int* __restrict__ rows,
                                        const int* __restrict__ cols, const float* __restrict__ w,
                                        float* __restrict__ out, int nnz) {
    int k = blockIdx.x * blockDim.x + threadIdx.x;
    if (k >= nnz) return;
    int n = blockIdx.y;
    int cf = flip_col(cols[k]);
    float v = w[k] * x[(size_t)n * N_A_CONST + cf];
    atomicAdd(out + (size_t)n * N_B_CONST + rows[k], v);
}

extern "C" void kernel_launch(void* const* d_in, const int* in_sizes, int n_in,
                              void* d_out, int out_size, void* d_ws, size_t ws_size,
                              hipStream_t stream) {
    const float* x    = (const float*)d_in[0];
    const int*   rows = (const int*)d_in[1];
    const int*   cols = (const int*)d_in[2];
    const float* w    = (const float*)d_in[3];
    float* out = (float*)d_out;

    int nnz    = in_sizes[1];
    int nfield = in_sizes[0] / N_A_CONST;   // 140
    int npass  = (nfield + FPP - 1) / FPP;  // 5

    // ws layout (int units). Count/cursor arrays first: zeroed by one kernel.
    size_t o = 0;
    size_t bcount_o = o; o += NBUCK;
    size_t bcur_o   = o; o += NBUCK;
    size_t rcount_o = o; o += N_B_CONST;
    size_t rcur_o   = o; o += N_B_CONST;
    size_t zero_span = o;
    size_t boff_o   = o; o += NBUCK + 1;
    size_t roff_o   = o; o += N_B_CONST + 1;
    o = (o + 31) & ~(size_t)31;                // 128B-align perm
    size_t perm_o   = o; o += 4 * (size_t)nnz; // int4
    o = (o + 31) & ~(size_t)31;                // 128B-align g
    size_t g_o      = o;
    size_t need_bytes = (g_o + (size_t)nnz * GROW) * sizeof(int);

    if (ws_size < need_bytes) {
        zero_out_kernel<<<2048, 256, 0, stream>>>(out, out_size);
        dim3 grid((nnz + 255) / 256, nfield);
        scatter_fallback_kernel<<<grid, 256, 0, stream>>>(x, rows, cols, w, out, nnz);
        return;
    }

    int*  wsI    = (int*)d_ws;
    int*  bcount = wsI + bcount_o;
    int*  bcur   = wsI + bcur_o;
    int*  rcount = wsI + rcount_o;
    int*  rcur   = wsI + rcur_o;
    int*  boff   = wsI + boff_o;
    int*  roff   = wsI + roff_o;
    int4* perm   = (int4*)(wsI + perm_o);
    float* g     = (float*)(wsI + g_o);

    zero_ws_kernel<<<512, 256, 0, stream>>>(wsI, (int)zero_span);

    int nblk = (nnz + 255) / 256;
    hist2_kernel<<<nblk, 256, 0, stream>>>(rows, cols, bcount, rcount, nnz);
    scan2_kernel<<<2, 1024, 0, stream>>>(bcount, boff, rcount, roff);
    perm2_kernel<<<nblk, 256, 0, stream>>>(rows, cols, w, boff, bcur, roff, rcur, perm, nnz);

    dim3 ggrid(nblk, npass);
    gather_kernel<<<ggrid, 256, 0, stream>>>(x, perm, g, nnz, nfield);

    int rblk = (N_B_CONST + 63) / 64;   // 1019
    reduce_kernel<<<rblk, 256, 0, stream>>>(g, roff, out, nfield);
}